// Round 1
// baseline (1551.850 us; speedup 1.0000x reference)
//
#include <hip/hip_runtime.h>
#include <cstdint>

typedef _Float16 half8 __attribute__((ext_vector_type(8)));
typedef _Float16 half4v __attribute__((ext_vector_type(4)));
typedef float f32x4 __attribute__((ext_vector_type(4)));

__device__ __forceinline__ void async_copy16(const void* g, void* l) {
    __builtin_amdgcn_global_load_lds((const __attribute__((address_space(1))) void*)g,
                                     (__attribute__((address_space(3))) void*)l, 16, 0, 0);
}

// ---------------------------------------------------------------------------
// prep: w_s = kernel * (1/32)   [= 32 * (kernel/1024)], plus transposed copy.
// Also zeroes the grid-barrier counter for this launch (visible to the
// persistent kernel via the dispatch-boundary release/acquire).
// ---------------------------------------------------------------------------
__global__ __launch_bounds__(256) void prep_w(const float* __restrict__ K,
                                              _Float16* __restrict__ w0,
                                              _Float16* __restrict__ w0T,
                                              unsigned* __restrict__ cnt) {
    if (blockIdx.x == 0 && blockIdx.y == 0 && threadIdx.x == 0) *cnt = 0u;
    __shared__ float tile[64][65];
    const int t  = threadIdx.x;
    const int bi = blockIdx.y * 64;
    const int bj = blockIdx.x * 64;
    const int r0 = t >> 4;
    const int c4 = (t & 15) * 4;
#pragma unroll
    for (int rr = 0; rr < 4; ++rr) {
        int r = r0 + rr * 16;
        f32x4 v = *(const f32x4*)&K[(size_t)(bi + r) * 1024 + bj + c4];
        v *= 0.03125f;
        half4v h;
        h[0] = (_Float16)v[0]; h[1] = (_Float16)v[1];
        h[2] = (_Float16)v[2]; h[3] = (_Float16)v[3];
        *(half4v*)&w0[(size_t)(bi + r) * 1024 + bj + c4] = h;
        tile[r][c4 + 0] = v[0]; tile[r][c4 + 1] = v[1];
        tile[r][c4 + 2] = v[2]; tile[r][c4 + 3] = v[3];
    }
    __syncthreads();
    const int cT = t >> 4;
    const int rT = (t & 15) * 4;
#pragma unroll
    for (int cc = 0; cc < 4; ++cc) {
        int c = cT + cc * 16;
        half4v h;
        h[0] = (_Float16)tile[rT + 0][c]; h[1] = (_Float16)tile[rT + 1][c];
        h[2] = (_Float16)tile[rT + 2][c]; h[3] = (_Float16)tile[rT + 3][c];
        *(half4v*)&w0T[(size_t)(bj + c) * 1024 + bi + rT] = h;
    }
}

// ---------------------------------------------------------------------------
// Persistent Bjorck chain: 20 iterations x 2 GEMM phases in ONE kernel.
// 256 blocks x 512 threads, 64 KB LDS -> exactly 1 block/CU, all co-resident.
// Grid-wide sync: monotonic counter, agent-scope release add + relaxed poll +
// acquire fence. Eliminates 40 kernel-launch/drain gaps (~11 us each).
// Per phase: 64x64 tile, 8 waves (4m x 2n, 1x2 frags), BK=128 (8 iters),
// LDS dbuf, glds staging, XOR swizzle, XCD-patch block swizzle.
// ---------------------------------------------------------------------------
__global__ __launch_bounds__(512)
void bjorck_chain(_Float16* __restrict__ wh0, _Float16* __restrict__ wh1,
                  _Float16* __restrict__ wT0, _Float16* __restrict__ wT1,
                  _Float16* __restrict__ Sh,  unsigned* __restrict__ cnt) {
    __shared__ _Float16 sA[2][8192];   // 64 rows x 128 halves
    __shared__ _Float16 sB[2][8192];
    const int t = threadIdx.x;
    const int b = blockIdx.x;
    const int xcd = b & 7, j = b >> 3;
    const int m0 = (((xcd & 1) << 3) + (j & 7)) << 6;   // 16 m-tiles
    const int n0 = (((xcd >> 1) << 2) + (j >> 3)) << 6; // 16 n-tiles
    const int ln = t & 63, wv = t >> 6;
    const int wm = wv >> 1, wn = wv & 1;     // 4 x 2 waves
    const int q  = ln >> 4, l15 = ln & 15;

    unsigned phase = 0;

    auto gbar = [&]() {
        __syncthreads();                  // all waves' stores drained to L2
        ++phase;
        if (t == 0) {
            // release: writeback L2, bump counter at coherence point
            __hip_atomic_fetch_add(cnt, 1u, __ATOMIC_RELEASE, __HIP_MEMORY_SCOPE_AGENT);
            const unsigned tgt = phase * 256u;
            while (__hip_atomic_load(cnt, __ATOMIC_RELAXED, __HIP_MEMORY_SCOPE_AGENT) < tgt)
                __builtin_amdgcn_s_sleep(1);
            __threadfence();              // acquire: invalidate stale L1/L2 lines
        }
        __syncthreads();
    };

    // one 1024x1024x1024 GEMM phase: C[m][n] = sum_k A[m][k] * BT[n][k]
    // EPI==0: out = (fp16)acc                  (S_s = w_s^T w_s)
    // EPI==1: w' = 1.5*wcur - (0.5/1024)*acc   (+ transposed copy)
    auto run_gemm = [&](const _Float16* __restrict__ A, const _Float16* __restrict__ BT,
                        const _Float16* __restrict__ wcur, _Float16* __restrict__ out,
                        _Float16* __restrict__ outT, int EPI) {
        f32x4 acc[2];
#pragma unroll
        for (int jn = 0; jn < 2; ++jn) {
            acc[jn][0] = 0.f; acc[jn][1] = 0.f;
            acc[jn][2] = 0.f; acc[jn][3] = 0.f;
        }
        auto stage = [&](int buf, int k0) {
#pragma unroll
            for (int rnd = 0; rnd < 2; ++rnd) {
                int c = t + rnd * 512;          // granule 0..1023 (16 per row)
                int row = c >> 4, g = c & 15;
                int gs = g ^ (row & 15);        // XOR swizzle
                async_copy16(A + (size_t)(m0 + row) * 1024 + k0 + gs * 8, &sA[buf][c * 8]);
                async_copy16(BT + (size_t)(n0 + row) * 1024 + k0 + gs * 8, &sB[buf][c * 8]);
            }
        };
        auto frag = [&](const _Float16* s, int row, int kc) -> half8 {
            return *(const half8*)&s[row * 128 + ((kc ^ (row & 15)) << 3)];
        };

        stage(0, 0);
        int cur = 0;
#pragma unroll 1
        for (int it8 = 0; it8 < 8; ++it8) {
            __syncthreads();
            if (it8 < 7) stage(cur ^ 1, (it8 + 1) * 128);
#pragma unroll
            for (int kk = 0; kk < 4; ++kk) {
                half8 a0 = frag(sA[cur], wm * 16 + l15, kk * 4 + q);
                half8 b0 = frag(sB[cur], wn * 32 + 0  + l15, kk * 4 + q);
                half8 b1 = frag(sB[cur], wn * 32 + 16 + l15, kk * 4 + q);
                acc[0] = __builtin_amdgcn_mfma_f32_16x16x32_f16(a0, b0, acc[0], 0, 0, 0);
                acc[1] = __builtin_amdgcn_mfma_f32_16x16x32_f16(a0, b1, acc[1], 0, 0, 0);
            }
            cur ^= 1;
        }

        const int row0 = m0 + wm * 16 + q * 4;
#pragma unroll
        for (int jn = 0; jn < 2; ++jn) {
            int col = n0 + wn * 32 + jn * 16 + l15;
            if (EPI == 0) {
#pragma unroll
                for (int r = 0; r < 4; ++r)
                    out[(size_t)(row0 + r) * 1024 + col] = (_Float16)acc[jn][r];
            } else {
                half4v hT;
#pragma unroll
                for (int r = 0; r < 4; ++r) {
                    float w0v = (float)wcur[(size_t)(row0 + r) * 1024 + col];
                    float nv  = 1.5f * w0v - 4.8828125e-4f * acc[jn][r];
                    _Float16 h = (_Float16)nv;
                    out[(size_t)(row0 + r) * 1024 + col] = h;
                    hT[r] = h;
                }
                *(half4v*)&outT[(size_t)col * 1024 + row0] = hT;
            }
        }
    };

#pragma unroll 1
    for (int it = 0; it < 20; ++it) {
        _Float16* whc = (it & 1) ? wh1 : wh0;
        _Float16* whn = (it & 1) ? wh0 : wh1;
        _Float16* wTc = (it & 1) ? wT1 : wT0;
        _Float16* wTn = (it & 1) ? wT0 : wT1;
        // S_s = w_s^T w_s : A = BT = wT (both row-slabs of w^T, k contiguous)
        run_gemm(wTc, wTc, nullptr, Sh, nullptr, 0);
        gbar();
        // w_next = 1.5 w - (0.5/1024) * (w_s * S_s); BT = S (symmetric)
        run_gemm(whc, Sh, whc, whn, wTn, 1);
        gbar();
    }
}

// ---------------------------------------------------------------------------
// big GEMM: Y[32768][1024] = (1/32) * X(f32, cvt->f16) * w_s  + bias
// 128x128 tile, BK=32, 4 waves (2x2, each 64x64 = 4x4 frags), dbuf.
// A staged via VGPR (fp32 load -> cvt -> ds_write, padded rows), B via glds.
// v4 grid: 1-D 2048 blocks; per-XCD round = 4 m-tiles x 8 n-tiles so the 8
// n-blocks sharing one X m-tile run CONCURRENTLY on the same XCD
// (X 2 MB + B 2 MB = L2-resident -> X fetched ~once chip-wide).
// Y stores non-temporal so the 128 MB write stream doesn't evict X/B from L2.
// ---------------------------------------------------------------------------
__global__ __launch_bounds__(256) void gemm_big(const float* __restrict__ X,
                                                const _Float16* __restrict__ BT,
                                                const float* __restrict__ bias,
                                                float* __restrict__ Y) {
    __shared__ _Float16 sA[2][128 * 40];   // pad: 40 halves/row
    __shared__ _Float16 sB[2][128 * 32];
    const int t   = threadIdx.x;
    const int bb  = blockIdx.x;
    const int xcd = bb & 7;
    const int jj  = bb >> 3;          // 0..255
    const int rr  = jj >> 5;          // round 0..7
    const int ss  = jj & 31;          // slot within round
    const int mt  = rr * 32 + xcd * 4 + (ss >> 3);  // 0..255
    const int nt  = ss & 7;                          // 0..7
    const int m0 = mt * 128, n0 = nt * 128;
    const int ln = t & 63, wv = t >> 6;
    const int wm = wv >> 1, wn = wv & 1;
    const int q  = ln >> 4, l15 = ln & 15;

    f32x4 acc[4][4];
#pragma unroll
    for (int i = 0; i < 4; ++i)
#pragma unroll
        for (int j = 0; j < 4; ++j) {
            acc[i][j][0] = 0.f; acc[i][j][1] = 0.f;
            acc[i][j][2] = 0.f; acc[i][j][3] = 0.f;
        }

    auto loadA = [&](int k0, f32x4* va) {
#pragma unroll
        for (int rnd = 0; rnd < 4; ++rnd) {
            int c = t + rnd * 256;          // 0..1023 float4-chunks (8/row)
            int row = c >> 3, s4 = c & 7;
            va[rnd] = *(const f32x4*)&X[(size_t)(m0 + row) * 1024 + k0 + s4 * 4];
        }
    };
    auto writeA = [&](int buf, const f32x4* va) {
#pragma unroll
        for (int rnd = 0; rnd < 4; ++rnd) {
            int c = t + rnd * 256;
            int row = c >> 3, s4 = c & 7;
            half4v h;
            h[0] = (_Float16)va[rnd][0]; h[1] = (_Float16)va[rnd][1];
            h[2] = (_Float16)va[rnd][2]; h[3] = (_Float16)va[rnd][3];
            *(half4v*)&sA[buf][row * 40 + s4 * 4] = h;
        }
    };
    auto stageB = [&](int buf, int k0) {
#pragma unroll
        for (int rnd = 0; rnd < 2; ++rnd) {
            int c = t + rnd * 256;          // 0..511 (4 chunks/row)
            int row = c >> 2, s = c & 3;
            int gs = s ^ ((row >> 1) & 3);
            async_copy16(BT + (size_t)(n0 + row) * 1024 + k0 + gs * 8, &sB[buf][c * 8]);
        }
    };

    f32x4 va[4];
    loadA(0, va);
    stageB(0, 0);
    writeA(0, va);
    int cur = 0;
#pragma unroll 1
    for (int it = 0; it < 32; ++it) {
        __syncthreads();
        if (it < 31) {
            loadA((it + 1) * 32, va);       // issue early; consumed after compute
            stageB(cur ^ 1, (it + 1) * 32);
        }
        half8 a[4], bfr[4];
#pragma unroll
        for (int im = 0; im < 4; ++im) {
            int row = wm * 64 + im * 16 + l15;
            a[im] = *(const half8*)&sA[cur][row * 40 + q * 8];
        }
#pragma unroll
        for (int jn = 0; jn < 4; ++jn) {
            int row = wn * 64 + jn * 16 + l15;
            bfr[jn] = *(const half8*)&sB[cur][row * 32 + ((q ^ ((row >> 1) & 3)) << 3)];
        }
#pragma unroll
        for (int im = 0; im < 4; ++im)
#pragma unroll
            for (int jn = 0; jn < 4; ++jn)
                acc[im][jn] = __builtin_amdgcn_mfma_f32_16x16x32_f16(a[im], bfr[jn], acc[im][jn], 0, 0, 0);
        if (it < 31) writeA(cur ^ 1, va);
        cur ^= 1;
    }

#pragma unroll
    for (int jn = 0; jn < 4; ++jn) {
        int col = n0 + wn * 64 + jn * 16 + l15;
        float bv = bias[col];
#pragma unroll
        for (int im = 0; im < 4; ++im) {
            int row0 = m0 + wm * 64 + im * 16 + q * 4;
#pragma unroll
            for (int r = 0; r < 4; ++r)
                __builtin_nontemporal_store(acc[im][jn][r] * 0.03125f + bv,
                                            &Y[(size_t)(row0 + r) * 1024 + col]);
        }
    }
}

// ---------------------------------------------------------------------------
extern "C" void kernel_launch(void* const* d_in, const int* in_sizes, int n_in,
                              void* d_out, int out_size, void* d_ws, size_t ws_size,
                              hipStream_t stream) {
    (void)in_sizes; (void)n_in; (void)out_size; (void)ws_size;
    const float* x    = (const float*)d_in[0];
    const float* kern = (const float*)d_in[1];
    const float* bias = (const float*)d_in[2];
    float* y = (float*)d_out;

    char* ws = (char*)d_ws;
    const size_t SZ = (size_t)1024 * 1024 * sizeof(_Float16);  // 2 MB
    _Float16* wh[2] = {(_Float16*)(ws + 0 * SZ), (_Float16*)(ws + 1 * SZ)};
    _Float16* wT[2] = {(_Float16*)(ws + 2 * SZ), (_Float16*)(ws + 3 * SZ)};
    _Float16* Sh    = (_Float16*)(ws + 4 * SZ);
    unsigned* cnt   = (unsigned*)(ws + 5 * SZ);

    prep_w<<<dim3(16, 16), 256, 0, stream>>>(kern, wh[0], wT[0], cnt);

    // whole 20-iteration Bjorck chain in one persistent kernel (40 phases,
    // hand-rolled agent-scope grid barrier; 256 blocks = 1/CU, co-resident)
    bjorck_chain<<<256, 512, 0, stream>>>(wh[0], wh[1], wT[0], wT[1], Sh, cnt);

    // final: y = (1/32) x * w_s + bias ; BT = wT (final parity lands in slot 0)
    gemm_big<<<2048, 256, 0, stream>>>(x, wT[0], bias, y);
}

// Round 2
// 764.577 us; speedup vs baseline: 2.0297x; 2.0297x over previous
//
#include <hip/hip_runtime.h>
#include <cstdint>

typedef _Float16 half8 __attribute__((ext_vector_type(8)));
typedef _Float16 half4v __attribute__((ext_vector_type(4)));
typedef float f32x4 __attribute__((ext_vector_type(4)));

__device__ __forceinline__ void async_copy16(const void* g, void* l) {
    __builtin_amdgcn_global_load_lds((const __attribute__((address_space(1))) void*)g,
                                     (__attribute__((address_space(3))) void*)l, 16, 0, 0);
}

// ---------------------------------------------------------------------------
// prep: w_s = kernel * (1/32)   [= 32 * (kernel/1024)], plus transposed copy.
// ---------------------------------------------------------------------------
__global__ __launch_bounds__(256) void prep_w(const float* __restrict__ K,
                                              _Float16* __restrict__ w0,
                                              _Float16* __restrict__ w0T) {
    __shared__ float tile[64][65];
    const int t  = threadIdx.x;
    const int bi = blockIdx.y * 64;
    const int bj = blockIdx.x * 64;
    const int r0 = t >> 4;
    const int c4 = (t & 15) * 4;
#pragma unroll
    for (int rr = 0; rr < 4; ++rr) {
        int r = r0 + rr * 16;
        f32x4 v = *(const f32x4*)&K[(size_t)(bi + r) * 1024 + bj + c4];
        v *= 0.03125f;
        half4v h;
        h[0] = (_Float16)v[0]; h[1] = (_Float16)v[1];
        h[2] = (_Float16)v[2]; h[3] = (_Float16)v[3];
        *(half4v*)&w0[(size_t)(bi + r) * 1024 + bj + c4] = h;
        tile[r][c4 + 0] = v[0]; tile[r][c4 + 1] = v[1];
        tile[r][c4 + 2] = v[2]; tile[r][c4 + 3] = v[3];
    }
    __syncthreads();
    const int cT = t >> 4;
    const int rT = (t & 15) * 4;
#pragma unroll
    for (int cc = 0; cc < 4; ++cc) {
        int c = cT + cc * 16;
        half4v h;
        h[0] = (_Float16)tile[rT + 0][c]; h[1] = (_Float16)tile[rT + 1][c];
        h[2] = (_Float16)tile[rT + 2][c]; h[3] = (_Float16)tile[rT + 3][c];
        *(half4v*)&w0T[(size_t)(bj + c) * 1024 + bi + rT] = h;
    }
}

// ---------------------------------------------------------------------------
// small 1024x1024x1024 GEMM:  C[m][n] = sum_k A[m][k] * BT[n][k]
// EPI==0: out = (fp16)acc                  (S_s = w_s^T w_s, via A=BT=wT)
// EPI==1: w' = 1.5*wcur - (0.5/1024)*acc   (+ transposed copy)
// v2: 64x64 tile, 512 threads (8 waves = 2/SIMD: 4m x 2n, 1x2 frags each),
// BK=128 (8 iters), LDS dbuf 64 KB, glds staging, XOR swizzle,
// XCD-patch block swizzle (each XCD reads an 8m x 4n patch: 1.5 MB).
// NOTE: per-launch chain (NOT persistent). Round-1 measured: a persistent
// grid-barrier version costs ~30 us/phase (agent-scope wbl2/inv per block +
// hot-line atomic serialization) vs 14.1 us/phase here — launches keep L2
// warm for free. Do not re-fuse.
// ---------------------------------------------------------------------------
template <int EPI>
__global__ __launch_bounds__(512) void gemm1k(const _Float16* __restrict__ A,
                                              const _Float16* __restrict__ BT,
                                              const _Float16* __restrict__ wcur,
                                              _Float16* __restrict__ out,
                                              _Float16* __restrict__ outT) {
    __shared__ _Float16 sA[2][8192];   // 64 rows x 128 halves
    __shared__ _Float16 sB[2][8192];
    const int t = threadIdx.x;
    const int b = blockIdx.x;
    const int xcd = b & 7, j = b >> 3;
    const int m0 = (((xcd & 1) << 3) + (j & 7)) << 6;   // 16 m-tiles
    const int n0 = (((xcd >> 1) << 2) + (j >> 3)) << 6; // 16 n-tiles
    const int ln = t & 63, wv = t >> 6;
    const int wm = wv >> 1, wn = wv & 1;     // 4 x 2 waves
    const int q  = ln >> 4, l15 = ln & 15;

    f32x4 acc[2];
#pragma unroll
    for (int jn = 0; jn < 2; ++jn) {
        acc[jn][0] = 0.f; acc[jn][1] = 0.f;
        acc[jn][2] = 0.f; acc[jn][3] = 0.f;
    }

    auto stage = [&](int buf, int k0) {
#pragma unroll
        for (int rnd = 0; rnd < 2; ++rnd) {
            int c = t + rnd * 512;          // granule 0..1023 (16 per row)
            int row = c >> 4, g = c & 15;
            int gs = g ^ (row & 15);        // XOR swizzle
            async_copy16(A + (size_t)(m0 + row) * 1024 + k0 + gs * 8, &sA[buf][c * 8]);
            async_copy16(BT + (size_t)(n0 + row) * 1024 + k0 + gs * 8, &sB[buf][c * 8]);
        }
    };
    auto frag = [&](const _Float16* s, int row, int kc) -> half8 {
        return *(const half8*)&s[row * 128 + ((kc ^ (row & 15)) << 3)];
    };

    stage(0, 0);
    int cur = 0;
#pragma unroll 1
    for (int it = 0; it < 8; ++it) {
        __syncthreads();
        if (it < 7) stage(cur ^ 1, (it + 1) * 128);
#pragma unroll
        for (int kk = 0; kk < 4; ++kk) {
            half8 a0 = frag(sA[cur], wm * 16 + l15, kk * 4 + q);
            half8 b0 = frag(sB[cur], wn * 32 + 0  + l15, kk * 4 + q);
            half8 b1 = frag(sB[cur], wn * 32 + 16 + l15, kk * 4 + q);
            acc[0] = __builtin_amdgcn_mfma_f32_16x16x32_f16(a0, b0, acc[0], 0, 0, 0);
            acc[1] = __builtin_amdgcn_mfma_f32_16x16x32_f16(a0, b1, acc[1], 0, 0, 0);
        }
        cur ^= 1;
    }

    const int row0 = m0 + wm * 16 + q * 4;
#pragma unroll
    for (int jn = 0; jn < 2; ++jn) {
        int col = n0 + wn * 32 + jn * 16 + l15;
        if (EPI == 0) {
#pragma unroll
            for (int r = 0; r < 4; ++r)
                out[(size_t)(row0 + r) * 1024 + col] = (_Float16)acc[jn][r];
        } else {
            half4v hT;
#pragma unroll
            for (int r = 0; r < 4; ++r) {
                float w0v = (float)wcur[(size_t)(row0 + r) * 1024 + col];
                float nv  = 1.5f * w0v - 4.8828125e-4f * acc[jn][r];
                _Float16 h = (_Float16)nv;
                out[(size_t)(row0 + r) * 1024 + col] = h;
                hT[r] = h;
            }
            *(half4v*)&outT[(size_t)col * 1024 + row0] = hT;
        }
    }
}

// ---------------------------------------------------------------------------
// big GEMM: Y[32768][1024] = (1/32) * X(f32, cvt->f16) * w_s  + bias
// 128x128 tile, BK=32, 4 waves (2x2, each 64x64 = 4x4 frags), dbuf.
// A staged via VGPR (fp32 load -> cvt -> ds_write, padded rows), B via glds.
// v5 grid: 1-D 2048 blocks; per-XCD round = 4 m-tiles x 8 n-tiles so the 8
// n-blocks sharing one X m-tile run CONCURRENTLY on the same XCD
// (X 2 MB + B 2 MB = L2-resident -> X fetched ~once chip-wide).
// Plain Y stores (round-1 measured: nontemporal stores regressed ~2x —
// partial-line writes bypass L2 write-coalescing).
// ---------------------------------------------------------------------------
__global__ __launch_bounds__(256) void gemm_big(const float* __restrict__ X,
                                                const _Float16* __restrict__ BT,
                                                const float* __restrict__ bias,
                                                float* __restrict__ Y) {
    __shared__ _Float16 sA[2][128 * 40];   // pad: 40 halves/row
    __shared__ _Float16 sB[2][128 * 32];
    const int t   = threadIdx.x;
    const int bb  = blockIdx.x;
    const int xcd = bb & 7;
    const int jj  = bb >> 3;          // 0..255
    const int rr  = jj >> 5;          // round 0..7
    const int ss  = jj & 31;          // slot within round
    const int mt  = rr * 32 + xcd * 4 + (ss >> 3);  // 0..255
    const int nt  = ss & 7;                          // 0..7
    const int m0 = mt * 128, n0 = nt * 128;
    const int ln = t & 63, wv = t >> 6;
    const int wm = wv >> 1, wn = wv & 1;
    const int q  = ln >> 4, l15 = ln & 15;

    f32x4 acc[4][4];
#pragma unroll
    for (int i = 0; i < 4; ++i)
#pragma unroll
        for (int j = 0; j < 4; ++j) {
            acc[i][j][0] = 0.f; acc[i][j][1] = 0.f;
            acc[i][j][2] = 0.f; acc[i][j][3] = 0.f;
        }

    auto loadA = [&](int k0, f32x4* va) {
#pragma unroll
        for (int rnd = 0; rnd < 4; ++rnd) {
            int c = t + rnd * 256;          // 0..1023 float4-chunks (8/row)
            int row = c >> 3, s4 = c & 7;
            va[rnd] = *(const f32x4*)&X[(size_t)(m0 + row) * 1024 + k0 + s4 * 4];
        }
    };
    auto writeA = [&](int buf, const f32x4* va) {
#pragma unroll
        for (int rnd = 0; rnd < 4; ++rnd) {
            int c = t + rnd * 256;
            int row = c >> 3, s4 = c & 7;
            half4v h;
            h[0] = (_Float16)va[rnd][0]; h[1] = (_Float16)va[rnd][1];
            h[2] = (_Float16)va[rnd][2]; h[3] = (_Float16)va[rnd][3];
            *(half4v*)&sA[buf][row * 40 + s4 * 4] = h;
        }
    };
    auto stageB = [&](int buf, int k0) {
#pragma unroll
        for (int rnd = 0; rnd < 2; ++rnd) {
            int c = t + rnd * 256;          // 0..511 (4 chunks/row)
            int row = c >> 2, s = c & 3;
            int gs = s ^ ((row >> 1) & 3);
            async_copy16(BT + (size_t)(n0 + row) * 1024 + k0 + gs * 8, &sB[buf][c * 8]);
        }
    };

    f32x4 va[4];
    loadA(0, va);
    stageB(0, 0);
    writeA(0, va);
    int cur = 0;
#pragma unroll 1
    for (int it = 0; it < 32; ++it) {
        __syncthreads();
        if (it < 31) {
            loadA((it + 1) * 32, va);       // issue early; consumed after compute
            stageB(cur ^ 1, (it + 1) * 32);
        }
        half8 a[4], bfr[4];
#pragma unroll
        for (int im = 0; im < 4; ++im) {
            int row = wm * 64 + im * 16 + l15;
            a[im] = *(const half8*)&sA[cur][row * 40 + q * 8];
        }
#pragma unroll
        for (int jn = 0; jn < 4; ++jn) {
            int row = wn * 64 + jn * 16 + l15;
            bfr[jn] = *(const half8*)&sB[cur][row * 32 + ((q ^ ((row >> 1) & 3)) << 3)];
        }
#pragma unroll
        for (int im = 0; im < 4; ++im)
#pragma unroll
            for (int jn = 0; jn < 4; ++jn)
                acc[im][jn] = __builtin_amdgcn_mfma_f32_16x16x32_f16(a[im], bfr[jn], acc[im][jn], 0, 0, 0);
        if (it < 31) writeA(cur ^ 1, va);
        cur ^= 1;
    }

#pragma unroll
    for (int jn = 0; jn < 4; ++jn) {
        int col = n0 + wn * 64 + jn * 16 + l15;
        float bv = bias[col];
#pragma unroll
        for (int im = 0; im < 4; ++im) {
            int row0 = m0 + wm * 64 + im * 16 + q * 4;
#pragma unroll
            for (int r = 0; r < 4; ++r)
                Y[(size_t)(row0 + r) * 1024 + col] = acc[im][jn][r] * 0.03125f + bv;
        }
    }
}

// ---------------------------------------------------------------------------
extern "C" void kernel_launch(void* const* d_in, const int* in_sizes, int n_in,
                              void* d_out, int out_size, void* d_ws, size_t ws_size,
                              hipStream_t stream) {
    (void)in_sizes; (void)n_in; (void)out_size; (void)ws_size;
    const float* x    = (const float*)d_in[0];
    const float* kern = (const float*)d_in[1];
    const float* bias = (const float*)d_in[2];
    float* y = (float*)d_out;

    char* ws = (char*)d_ws;
    const size_t SZ = (size_t)1024 * 1024 * sizeof(_Float16);  // 2 MB
    _Float16* wh[2] = {(_Float16*)(ws + 0 * SZ), (_Float16*)(ws + 1 * SZ)};
    _Float16* wT[2] = {(_Float16*)(ws + 2 * SZ), (_Float16*)(ws + 3 * SZ)};
    _Float16* Sh    = (_Float16*)(ws + 4 * SZ);

    prep_w<<<dim3(16, 16), 256, 0, stream>>>(kern, wh[0], wT[0]);

    for (int it = 0; it < 20; ++it) {
        int c = it & 1, n = c ^ 1;
        // S_s = w_s^T w_s : A = BT = wT (both row-slabs of w^T, k contiguous)
        gemm1k<0><<<256, 512, 0, stream>>>(wT[c], wT[c], nullptr, Sh, nullptr);
        // w_next = 1.5 w - (0.5/1024) * (w_s * S_s); BT = S (symmetric)
        gemm1k<1><<<256, 512, 0, stream>>>(wh[c], Sh, wh[c], wh[n], wT[n]);
    }
    // final: y = (1/32) x * w_s + bias ; BT = wT (final parity lands in slot 0)
    gemm_big<<<2048, 256, 0, stream>>>(x, wT[0], bias, y);
}

// Round 3
// 750.341 us; speedup vs baseline: 2.0682x; 1.0190x over previous
//
#include <hip/hip_runtime.h>
#include <cstdint>

typedef _Float16 half8 __attribute__((ext_vector_type(8)));
typedef _Float16 half4v __attribute__((ext_vector_type(4)));
typedef float f32x4 __attribute__((ext_vector_type(4)));

__device__ __forceinline__ void async_copy16(const void* g, void* l) {
    __builtin_amdgcn_global_load_lds((const __attribute__((address_space(1))) void*)g,
                                     (__attribute__((address_space(3))) void*)l, 16, 0, 0);
}

// ---------------------------------------------------------------------------
// prep: w_s = kernel * (1/32)   [= 32 * (kernel/1024)], plus transposed copy.
// ---------------------------------------------------------------------------
__global__ __launch_bounds__(256) void prep_w(const float* __restrict__ K,
                                              _Float16* __restrict__ w0,
                                              _Float16* __restrict__ w0T) {
    __shared__ float tile[64][65];
    const int t  = threadIdx.x;
    const int bi = blockIdx.y * 64;
    const int bj = blockIdx.x * 64;
    const int r0 = t >> 4;
    const int c4 = (t & 15) * 4;
#pragma unroll
    for (int rr = 0; rr < 4; ++rr) {
        int r = r0 + rr * 16;
        f32x4 v = *(const f32x4*)&K[(size_t)(bi + r) * 1024 + bj + c4];
        v *= 0.03125f;
        half4v h;
        h[0] = (_Float16)v[0]; h[1] = (_Float16)v[1];
        h[2] = (_Float16)v[2]; h[3] = (_Float16)v[3];
        *(half4v*)&w0[(size_t)(bi + r) * 1024 + bj + c4] = h;
        tile[r][c4 + 0] = v[0]; tile[r][c4 + 1] = v[1];
        tile[r][c4 + 2] = v[2]; tile[r][c4 + 3] = v[3];
    }
    __syncthreads();
    const int cT = t >> 4;
    const int rT = (t & 15) * 4;
#pragma unroll
    for (int cc = 0; cc < 4; ++cc) {
        int c = cT + cc * 16;
        half4v h;
        h[0] = (_Float16)tile[rT + 0][c]; h[1] = (_Float16)tile[rT + 1][c];
        h[2] = (_Float16)tile[rT + 2][c]; h[3] = (_Float16)tile[rT + 3][c];
        *(half4v*)&w0T[(size_t)(bj + c) * 1024 + bi + rT] = h;
    }
}

// ---------------------------------------------------------------------------
// small 1024x1024x1024 GEMM:  C[m][n] = sum_k A[m][k] * BT[n][k]
// EPI==0: out = (fp16)acc                  (S_s = w_s^T w_s, via A=BT=wT)
// EPI==1: w' = 1.5*wcur - (0.5/1024)*acc   (+ transposed copy)
// v3: 3-buffer LDS (96 KB) + raw s_barrier + COUNTED vmcnt(4) — the stage of
// tile t+1 stays in flight across the barrier (round-2 measured: __syncthreads
// drains vmcnt(0), exposing full load latency each of the 8 K-steps).
// FIFO argument: >=4 vmcnt entries are always newer than stage(t), so
// vmcnt(4) => stage(t) retired wave-locally; barrier makes it grid... wave-
// group-wide. Last step peeled with vmcnt(0).
// NOTE: per-launch chain (NOT persistent; round-1: persistent grid barrier
// costs ~30us/phase). Do not re-fuse.
// ---------------------------------------------------------------------------
template <int EPI>
__global__ __launch_bounds__(512) void gemm1k(const _Float16* __restrict__ A,
                                              const _Float16* __restrict__ BT,
                                              const _Float16* __restrict__ wcur,
                                              _Float16* __restrict__ out,
                                              _Float16* __restrict__ outT) {
    __shared__ _Float16 sA[3][8192];   // 64 rows x 128 halves per buf
    __shared__ _Float16 sB[3][8192];
    const int t = threadIdx.x;
    const int b = blockIdx.x;
    const int xcd = b & 7, j = b >> 3;
    const int m0 = (((xcd & 1) << 3) + (j & 7)) << 6;   // 16 m-tiles
    const int n0 = (((xcd >> 1) << 2) + (j >> 3)) << 6; // 16 n-tiles
    const int ln = t & 63, wv = t >> 6;
    const int wm = wv >> 1, wn = wv & 1;     // 4 x 2 waves
    const int q  = ln >> 4, l15 = ln & 15;
    const int row0 = m0 + wm * 16 + q * 4;

    // EPI==1: prefetch wcur for the epilogue. Issued BEFORE the stages so
    // these entries are older in the vmcnt FIFO (counted waits stay valid:
    // any interleave still leaves >=4 entries newer than stage(t)).
    float wpre[2][4];
    if (EPI == 1) {
#pragma unroll
        for (int jn = 0; jn < 2; ++jn) {
            int col = n0 + wn * 32 + jn * 16 + l15;
#pragma unroll
            for (int r = 0; r < 4; ++r)
                wpre[jn][r] = (float)wcur[(size_t)(row0 + r) * 1024 + col];
        }
    }

    f32x4 acc[2];
#pragma unroll
    for (int jn = 0; jn < 2; ++jn) {
        acc[jn][0] = 0.f; acc[jn][1] = 0.f;
        acc[jn][2] = 0.f; acc[jn][3] = 0.f;
    }

    auto stage = [&](int buf, int k0) {   // 4 vmcnt entries per thread
#pragma unroll
        for (int rnd = 0; rnd < 2; ++rnd) {
            int c = t + rnd * 512;          // granule 0..1023 (16 per row)
            int row = c >> 4, g = c & 15;
            int gs = g ^ (row & 15);        // XOR swizzle
            async_copy16(A + (size_t)(m0 + row) * 1024 + k0 + gs * 8, &sA[buf][c * 8]);
            async_copy16(BT + (size_t)(n0 + row) * 1024 + k0 + gs * 8, &sB[buf][c * 8]);
        }
    };
    auto frag = [&](const _Float16* s, int row, int kc) -> half8 {
        return *(const half8*)&s[row * 128 + ((kc ^ (row & 15)) << 3)];
    };
    auto dostep = [&](int buf) {
#pragma unroll
        for (int kk = 0; kk < 4; ++kk) {
            half8 a0 = frag(sA[buf], wm * 16 + l15, kk * 4 + q);
            half8 b0 = frag(sB[buf], wn * 32 + 0  + l15, kk * 4 + q);
            half8 b1 = frag(sB[buf], wn * 32 + 16 + l15, kk * 4 + q);
            acc[0] = __builtin_amdgcn_mfma_f32_16x16x32_f16(a0, b0, acc[0], 0, 0, 0);
            acc[1] = __builtin_amdgcn_mfma_f32_16x16x32_f16(a0, b1, acc[1], 0, 0, 0);
        }
    };

    stage(0, 0);
    stage(1, 128);
#pragma unroll 1
    for (int it = 0; it < 7; ++it) {
        // wait: stage(it) done (stage(it+1) may remain in flight); then barrier.
        asm volatile("s_waitcnt vmcnt(4)\n\ts_barrier" ::: "memory");
        if (it < 6) stage((it + 2) % 3, (it + 2) * 128);  // buf's last reader was
                                                          // compute(it-1): done at barrier
        dostep(it % 3);
    }
    asm volatile("s_waitcnt vmcnt(0)\n\ts_barrier" ::: "memory");
    dostep(1);   // it = 7 -> buf 1

    // epilogue
#pragma unroll
    for (int jn = 0; jn < 2; ++jn) {
        int col = n0 + wn * 32 + jn * 16 + l15;
        if (EPI == 0) {
#pragma unroll
            for (int r = 0; r < 4; ++r)
                out[(size_t)(row0 + r) * 1024 + col] = (_Float16)acc[jn][r];
        } else {
            half4v hT;
#pragma unroll
            for (int r = 0; r < 4; ++r) {
                float nv  = 1.5f * wpre[jn][r] - 4.8828125e-4f * acc[jn][r];
                _Float16 h = (_Float16)nv;
                out[(size_t)(row0 + r) * 1024 + col] = h;
                hT[r] = h;
            }
            *(half4v*)&outT[(size_t)col * 1024 + row0] = hT;
        }
    }
}

// ---------------------------------------------------------------------------
// big GEMM: Y[32768][1024] = (1/32) * X(f32, cvt->f16) * w_s  + bias
// 128x128 tile, BK=32, 4 waves (2x2, each 64x64 = 4x4 frags).
// A: reg-staged (fp32 load -> cvt -> ds_write, padded rows), 2 LDS bufs,
//    2 register sets (vaA/vaB, statically indexed via unroll-by-2).
// B: glds, 3 LDS bufs, 2-deep prefetch.
// Phase gate: raw s_barrier + counted vmcnt(6) (= loadA(t+1)x4 + stageB(t+1)x2
// in flight) + lgkmcnt(0) (writeA(t) ds_writes visible). Round-2 measured:
// __syncthreads' vmcnt(0) drained the t+1 prefetch every step (latency-bound,
// MfmaUtil 13.5%, hbm 15% peak).
// Grid: per-XCD round = 4 m-tiles x 8 n-tiles -> X fetched once chip-wide
// (round-2 verified: FETCH 367->98 MB). LDS 45 KB -> 3 blocks/CU.
// Plain Y stores (round-1: nontemporal regressed ~2x).
// ---------------------------------------------------------------------------
__global__ __launch_bounds__(256) void gemm_big(const float* __restrict__ X,
                                                const _Float16* __restrict__ BT,
                                                const float* __restrict__ bias,
                                                float* __restrict__ Y) {
    __shared__ _Float16 sA[2][128 * 40];   // pad: 40 halves/row (10 KB/buf)
    __shared__ _Float16 sB[3][128 * 32];   // 8 KB/buf
    const int t   = threadIdx.x;
    const int bb  = blockIdx.x;
    const int xcd = bb & 7;
    const int jj  = bb >> 3;          // 0..255
    const int rr  = jj >> 5;          // round 0..7
    const int ss  = jj & 31;          // slot within round
    const int mt  = rr * 32 + xcd * 4 + (ss >> 3);  // 0..255
    const int nt  = ss & 7;                          // 0..7
    const int m0 = mt * 128, n0 = nt * 128;
    const int ln = t & 63, wv = t >> 6;
    const int wm = wv >> 1, wn = wv & 1;
    const int q  = ln >> 4, l15 = ln & 15;

    f32x4 acc[4][4];
#pragma unroll
    for (int i = 0; i < 4; ++i)
#pragma unroll
        for (int j = 0; j < 4; ++j) {
            acc[i][j][0] = 0.f; acc[i][j][1] = 0.f;
            acc[i][j][2] = 0.f; acc[i][j][3] = 0.f;
        }

    auto loadA = [&](int k0, f32x4* va) {   // 4 vmcnt entries
#pragma unroll
        for (int rnd = 0; rnd < 4; ++rnd) {
            int c = t + rnd * 256;          // 0..1023 float4-chunks (8/row)
            int row = c >> 3, s4 = c & 7;
            va[rnd] = *(const f32x4*)&X[(size_t)(m0 + row) * 1024 + k0 + s4 * 4];
        }
    };
    auto writeA = [&](int buf, const f32x4* va) {
#pragma unroll
        for (int rnd = 0; rnd < 4; ++rnd) {
            int c = t + rnd * 256;
            int row = c >> 3, s4 = c & 7;
            half4v h;
            h[0] = (_Float16)va[rnd][0]; h[1] = (_Float16)va[rnd][1];
            h[2] = (_Float16)va[rnd][2]; h[3] = (_Float16)va[rnd][3];
            *(half4v*)&sA[buf][row * 40 + s4 * 4] = h;
        }
    };
    auto stageB = [&](int buf, int k0) {    // 2 vmcnt entries
#pragma unroll
        for (int rnd = 0; rnd < 2; ++rnd) {
            int c = t + rnd * 256;          // 0..511 (4 chunks/row)
            int row = c >> 2, s = c & 3;
            int gs = s ^ ((row >> 1) & 3);
            async_copy16(BT + (size_t)(n0 + row) * 1024 + k0 + gs * 8, &sB[buf][c * 8]);
        }
    };
    auto compute = [&](int t_) {
        half8 a[4], bfr[4];
#pragma unroll
        for (int im = 0; im < 4; ++im) {
            int row = wm * 64 + im * 16 + l15;
            a[im] = *(const half8*)&sA[t_ & 1][row * 40 + q * 8];
        }
#pragma unroll
        for (int jn = 0; jn < 4; ++jn) {
            int row = wn * 64 + jn * 16 + l15;
            bfr[jn] = *(const half8*)&sB[t_ % 3][row * 32 + ((q ^ ((row >> 1) & 3)) << 3)];
        }
#pragma unroll
        for (int im = 0; im < 4; ++im)
#pragma unroll
            for (int jn = 0; jn < 4; ++jn)
                acc[im][jn] = __builtin_amdgcn_mfma_f32_16x16x32_f16(a[im], bfr[jn], acc[im][jn], 0, 0, 0);
    };

    f32x4 vaA[4], vaB[4];
    // prologue: A(0) -> LDS, B(0) + B(1) + A(1)-regs in flight
    loadA(0, vaA);
    stageB(0, 0);
    writeA(0, vaA);          // compiler waits vaA's loads; stageB(0) stays in flight
    loadA(32, vaB);
    stageB(1, 32);

    // body(t): wait{vmcnt(6): stageB(t) done, t+1 stream in flight; lgkm(0):
    // writeA(t) visible}; barrier; issue t+2 (B buf last read at t-1: done);
    // compute(t); writeA(t+1) from regs loaded at t-1.
#define BODY(T, VLD, VWR)                                                     \
    {                                                                         \
        asm volatile("s_waitcnt vmcnt(6) lgkmcnt(0)\n\ts_barrier" ::: "memory"); \
        if ((T) + 2 < 32) {                                                   \
            loadA(((T) + 2) * 32, VLD);                                       \
            stageB(((T) + 2) % 3, ((T) + 2) * 32);                            \
        }                                                                     \
        compute(T);                                                           \
        writeA(((T) + 1) & 1, VWR);                                           \
    }

#pragma unroll 1
    for (int tp = 0; tp < 15; ++tp) {
        int te = tp * 2;
        BODY(te, vaA, vaB);       // even: load -> vaA, write from vaB (=loadA(te+1))
        BODY(te + 1, vaB, vaA);   // odd:  load -> vaB, write from vaA (=loadA(te+2))
    }
    BODY(30, vaA, vaB);           // t=30 (no t+2 issue); writeA(31) from vaB
#undef BODY
    asm volatile("s_waitcnt vmcnt(0) lgkmcnt(0)\n\ts_barrier" ::: "memory");
    compute(31);

#pragma unroll
    for (int jn = 0; jn < 4; ++jn) {
        int col = n0 + wn * 64 + jn * 16 + l15;
        float bv = bias[col];
#pragma unroll
        for (int im = 0; im < 4; ++im) {
            int row0 = m0 + wm * 64 + im * 16 + q * 4;
#pragma unroll
            for (int r = 0; r < 4; ++r)
                Y[(size_t)(row0 + r) * 1024 + col] = acc[im][jn][r] * 0.03125f + bv;
        }
    }
}

// ---------------------------------------------------------------------------
extern "C" void kernel_launch(void* const* d_in, const int* in_sizes, int n_in,
                              void* d_out, int out_size, void* d_ws, size_t ws_size,
                              hipStream_t stream) {
    (void)in_sizes; (void)n_in; (void)out_size; (void)ws_size;
    const float* x    = (const float*)d_in[0];
    const float* kern = (const float*)d_in[1];
    const float* bias = (const float*)d_in[2];
    float* y = (float*)d_out;

    char* ws = (char*)d_ws;
    const size_t SZ = (size_t)1024 * 1024 * sizeof(_Float16);  // 2 MB
    _Float16* wh[2] = {(_Float16*)(ws + 0 * SZ), (_Float16*)(ws + 1 * SZ)};
    _Float16* wT[2] = {(_Float16*)(ws + 2 * SZ), (_Float16*)(ws + 3 * SZ)};
    _Float16* Sh    = (_Float16*)(ws + 4 * SZ);

    prep_w<<<dim3(16, 16), 256, 0, stream>>>(kern, wh[0], wT[0]);

    for (int it = 0; it < 20; ++it) {
        int c = it & 1, n = c ^ 1;
        // S_s = w_s^T w_s : A = BT = wT (both row-slabs of w^T, k contiguous)
        gemm1k<0><<<256, 512, 0, stream>>>(wT[c], wT[c], nullptr, Sh, nullptr);
        // w_next = 1.5 w - (0.5/1024) * (w_s * S_s); BT = S (symmetric)
        gemm1k<1><<<256, 512, 0, stream>>>(wh[c], Sh, wh[c], wh[n], wT[n]);
    }
    // final: y = (1/32) x * w_s + bias ; BT = wT (final parity lands in slot 0)
    gemm_big<<<2048, 256, 0, stream>>>(x, wT[0], bias, y);
}

// Round 4
// 725.296 us; speedup vs baseline: 2.1396x; 1.0345x over previous
//
#include <hip/hip_runtime.h>
#include <cstdint>

typedef _Float16 half8 __attribute__((ext_vector_type(8)));
typedef _Float16 half4v __attribute__((ext_vector_type(4)));
typedef float f32x4 __attribute__((ext_vector_type(4)));

__device__ __forceinline__ void async_copy16(const void* g, void* l) {
    __builtin_amdgcn_global_load_lds((const __attribute__((address_space(1))) void*)g,
                                     (__attribute__((address_space(3))) void*)l, 16, 0, 0);
}

// ---------------------------------------------------------------------------
// prep: w_s = kernel * (1/32)   [= 32 * (kernel/1024)], plus transposed copy.
// ---------------------------------------------------------------------------
__global__ __launch_bounds__(256) void prep_w(const float* __restrict__ K,
                                              _Float16* __restrict__ w0,
                                              _Float16* __restrict__ w0T) {
    __shared__ float tile[64][65];
    const int t  = threadIdx.x;
    const int bi = blockIdx.y * 64;
    const int bj = blockIdx.x * 64;
    const int r0 = t >> 4;
    const int c4 = (t & 15) * 4;
#pragma unroll
    for (int rr = 0; rr < 4; ++rr) {
        int r = r0 + rr * 16;
        f32x4 v = *(const f32x4*)&K[(size_t)(bi + r) * 1024 + bj + c4];
        v *= 0.03125f;
        half4v h;
        h[0] = (_Float16)v[0]; h[1] = (_Float16)v[1];
        h[2] = (_Float16)v[2]; h[3] = (_Float16)v[3];
        *(half4v*)&w0[(size_t)(bi + r) * 1024 + bj + c4] = h;
        tile[r][c4 + 0] = v[0]; tile[r][c4 + 1] = v[1];
        tile[r][c4 + 2] = v[2]; tile[r][c4 + 3] = v[3];
    }
    __syncthreads();
    const int cT = t >> 4;
    const int rT = (t & 15) * 4;
#pragma unroll
    for (int cc = 0; cc < 4; ++cc) {
        int c = cT + cc * 16;
        half4v h;
        h[0] = (_Float16)tile[rT + 0][c]; h[1] = (_Float16)tile[rT + 1][c];
        h[2] = (_Float16)tile[rT + 2][c]; h[3] = (_Float16)tile[rT + 3][c];
        *(half4v*)&w0T[(size_t)(bj + c) * 1024 + bi + rT] = h;
    }
}

// ---------------------------------------------------------------------------
// small 1024x1024x1024 GEMM:  C[m][n] = sum_k A[m][k] * BT[n][k]
// EPI==0: out = (fp16)acc                  (S_s = w_s^T w_s, via A=BT=wT)
// EPI==1: w' = 1.5*wcur - (0.5/1024)*acc   (+ transposed copy)
// v4: 4-buffer LDS (128 KB), 3-DEEP glds prefetch (12 outstanding entries per
// thread), counted vmcnt(8) steady-state, tail peeled vmcnt(4)/vmcnt(0).
// Theory: dispatch boundary invalidates L2 -> every launch starts cold on
// L3 (~600-900 cyc). Round-3's 2-deep pipeline left ~3-4k cyc/step exposed;
// 3 steps of slack + deeper MLP should cover it.
// Tile-t lives in buf t&3. stage(it+3) target buf last read at dostep(it-1);
// the wait-then-barrier at top of it makes all waves' stage(it) writes
// visible AND all waves past dostep(it-1) before any overwrite.
// NOTE: per-launch chain (round-1: persistent grid barrier costs ~30us/phase
// in agent-scope coherence). Do not re-fuse.
// ---------------------------------------------------------------------------
template <int EPI>
__global__ __launch_bounds__(512) void gemm1k(const _Float16* __restrict__ A,
                                              const _Float16* __restrict__ BT,
                                              const _Float16* __restrict__ wcur,
                                              _Float16* __restrict__ out,
                                              _Float16* __restrict__ outT) {
    __shared__ _Float16 sA[4][8192];   // 64 rows x 128 halves per buf (16 KB)
    __shared__ _Float16 sB[4][8192];   // total 128 KB
    const int t = threadIdx.x;
    const int b = blockIdx.x;
    const int xcd = b & 7, j = b >> 3;
    const int m0 = (((xcd & 1) << 3) + (j & 7)) << 6;   // 16 m-tiles
    const int n0 = (((xcd >> 1) << 2) + (j >> 3)) << 6; // 16 n-tiles
    const int ln = t & 63, wv = t >> 6;
    const int wm = wv >> 1, wn = wv & 1;     // 4 x 2 waves
    const int q  = ln >> 4, l15 = ln & 15;
    const int row0 = m0 + wm * 16 + q * 4;

    // EPI==1: prefetch wcur for the epilogue. Issued BEFORE the stages ->
    // oldest in the vmcnt FIFO; counted waits retire them first (harmless).
    float wpre[2][4];
    if (EPI == 1) {
#pragma unroll
        for (int jn = 0; jn < 2; ++jn) {
            int col = n0 + wn * 32 + jn * 16 + l15;
#pragma unroll
            for (int r = 0; r < 4; ++r)
                wpre[jn][r] = (float)wcur[(size_t)(row0 + r) * 1024 + col];
        }
    }

    f32x4 acc[2];
#pragma unroll
    for (int jn = 0; jn < 2; ++jn) {
        acc[jn][0] = 0.f; acc[jn][1] = 0.f;
        acc[jn][2] = 0.f; acc[jn][3] = 0.f;
    }

    auto stage = [&](int buf, int k0) {   // 4 vmcnt entries per thread
#pragma unroll
        for (int rnd = 0; rnd < 2; ++rnd) {
            int c = t + rnd * 512;          // granule 0..1023 (16 per row)
            int row = c >> 4, g = c & 15;
            int gs = g ^ (row & 15);        // XOR swizzle
            async_copy16(A + (size_t)(m0 + row) * 1024 + k0 + gs * 8, &sA[buf][c * 8]);
            async_copy16(BT + (size_t)(n0 + row) * 1024 + k0 + gs * 8, &sB[buf][c * 8]);
        }
    };
    auto frag = [&](const _Float16* s, int row, int kc) -> half8 {
        return *(const half8*)&s[row * 128 + ((kc ^ (row & 15)) << 3)];
    };
    auto dostep = [&](int buf) {
#pragma unroll
        for (int kk = 0; kk < 4; ++kk) {
            half8 a0 = frag(sA[buf], wm * 16 + l15, kk * 4 + q);
            half8 b0 = frag(sB[buf], wn * 32 + 0  + l15, kk * 4 + q);
            half8 b1 = frag(sB[buf], wn * 32 + 16 + l15, kk * 4 + q);
            acc[0] = __builtin_amdgcn_mfma_f32_16x16x32_f16(a0, b0, acc[0], 0, 0, 0);
            acc[1] = __builtin_amdgcn_mfma_f32_16x16x32_f16(a0, b1, acc[1], 0, 0, 0);
        }
    };

    stage(0, 0);
    stage(1, 128);
    stage(2, 256);
    // steady: at top of it, outstanding = stage(it)+stage(it+1)+stage(it+2)
    // = 12 entries; vmcnt(8) retires stage(it) only.
#pragma unroll 1
    for (int it = 0; it < 6; ++it) {
        asm volatile("s_waitcnt vmcnt(8)\n\ts_barrier" ::: "memory");
        if (it < 5) stage((it + 3) & 3, (it + 3) * 128);
        dostep(it & 3);
    }
    asm volatile("s_waitcnt vmcnt(4)\n\ts_barrier" ::: "memory");  // stage(6) done
    dostep(2);   // tile 6 -> buf 2
    asm volatile("s_waitcnt vmcnt(0)\n\ts_barrier" ::: "memory");  // stage(7) done
    dostep(3);   // tile 7 -> buf 3

    // epilogue
#pragma unroll
    for (int jn = 0; jn < 2; ++jn) {
        int col = n0 + wn * 32 + jn * 16 + l15;
        if (EPI == 0) {
#pragma unroll
            for (int r = 0; r < 4; ++r)
                out[(size_t)(row0 + r) * 1024 + col] = (_Float16)acc[jn][r];
        } else {
            half4v hT;
#pragma unroll
            for (int r = 0; r < 4; ++r) {
                float nv  = 1.5f * wpre[jn][r] - 4.8828125e-4f * acc[jn][r];
                _Float16 h = (_Float16)nv;
                out[(size_t)(row0 + r) * 1024 + col] = h;
                hT[r] = h;
            }
            *(half4v*)&outT[(size_t)col * 1024 + row0] = hT;
        }
    }
}

// ---------------------------------------------------------------------------
// big GEMM: Y[32768][1024] = (1/32) * X(f32, cvt->f16) * w_s  + bias
// 128x128 tile, BK=32, 4 waves (2x2, each 64x64 = 4x4 frags).
// A: reg-staged (fp32 load -> cvt -> ds_write, padded rows), 2 LDS bufs,
//    2 register sets (vaA/vaB, statically indexed via unroll-by-2).
// B: glds, v6: 4 LDS bufs, 3-DEEP prefetch (stageB(T+3) issued at T).
// Phase gate: raw s_barrier + counted vmcnt(8) steady (= B(T+1),A(T+1),B(T+2)
// in flight; retires stageB(T)) + lgkmcnt(0); tail vmcnt(6)/vmcnt(0).
// Grid: per-XCD round = 4 m-tiles x 8 n-tiles -> X fetched ~once chip-wide
// (round-2 verified: FETCH 367->98 MB). LDS 53 KB -> 3 blocks/CU.
// Plain Y stores (round-1: nontemporal regressed ~2x).
// ---------------------------------------------------------------------------
__global__ __launch_bounds__(256) void gemm_big(const float* __restrict__ X,
                                                const _Float16* __restrict__ BT,
                                                const float* __restrict__ bias,
                                                float* __restrict__ Y) {
    __shared__ _Float16 sA[2][128 * 40];   // pad: 40 halves/row (10 KB/buf)
    __shared__ _Float16 sB[4][128 * 32];   // 8 KB/buf
    const int t   = threadIdx.x;
    const int bb  = blockIdx.x;
    const int xcd = bb & 7;
    const int jj  = bb >> 3;          // 0..255
    const int rr  = jj >> 5;          // round 0..7
    const int ss  = jj & 31;          // slot within round
    const int mt  = rr * 32 + xcd * 4 + (ss >> 3);  // 0..255
    const int nt  = ss & 7;                          // 0..7
    const int m0 = mt * 128, n0 = nt * 128;
    const int ln = t & 63, wv = t >> 6;
    const int wm = wv >> 1, wn = wv & 1;
    const int q  = ln >> 4, l15 = ln & 15;

    f32x4 acc[4][4];
#pragma unroll
    for (int i = 0; i < 4; ++i)
#pragma unroll
        for (int j = 0; j < 4; ++j) {
            acc[i][j][0] = 0.f; acc[i][j][1] = 0.f;
            acc[i][j][2] = 0.f; acc[i][j][3] = 0.f;
        }

    auto loadA = [&](int k0, f32x4* va) {   // 4 vmcnt entries
#pragma unroll
        for (int rnd = 0; rnd < 4; ++rnd) {
            int c = t + rnd * 256;          // 0..1023 float4-chunks (8/row)
            int row = c >> 3, s4 = c & 7;
            va[rnd] = *(const f32x4*)&X[(size_t)(m0 + row) * 1024 + k0 + s4 * 4];
        }
    };
    auto writeA = [&](int buf, const f32x4* va) {
#pragma unroll
        for (int rnd = 0; rnd < 4; ++rnd) {
            int c = t + rnd * 256;
            int row = c >> 3, s4 = c & 7;
            half4v h;
            h[0] = (_Float16)va[rnd][0]; h[1] = (_Float16)va[rnd][1];
            h[2] = (_Float16)va[rnd][2]; h[3] = (_Float16)va[rnd][3];
            *(half4v*)&sA[buf][row * 40 + s4 * 4] = h;
        }
    };
    auto stageB = [&](int buf, int k0) {    // 2 vmcnt entries
#pragma unroll
        for (int rnd = 0; rnd < 2; ++rnd) {
            int c = t + rnd * 256;          // 0..511 (4 chunks/row)
            int row = c >> 2, s = c & 3;
            int gs = s ^ ((row >> 1) & 3);
            async_copy16(BT + (size_t)(n0 + row) * 1024 + k0 + gs * 8, &sB[buf][c * 8]);
        }
    };
    auto compute = [&](int t_) {
        half8 a[4], bfr[4];
#pragma unroll
        for (int im = 0; im < 4; ++im) {
            int row = wm * 64 + im * 16 + l15;
            a[im] = *(const half8*)&sA[t_ & 1][row * 40 + q * 8];
        }
#pragma unroll
        for (int jn = 0; jn < 4; ++jn) {
            int row = wn * 64 + jn * 16 + l15;
            bfr[jn] = *(const half8*)&sB[t_ & 3][row * 32 + ((q ^ ((row >> 1) & 3)) << 3)];
        }
#pragma unroll
        for (int im = 0; im < 4; ++im)
#pragma unroll
            for (int jn = 0; jn < 4; ++jn)
                acc[im][jn] = __builtin_amdgcn_mfma_f32_16x16x32_f16(a[im], bfr[jn], acc[im][jn], 0, 0, 0);
    };

    f32x4 vaA[4], vaB[4];
    // prologue: A(0) -> LDS; B(0),B(1),B(2) + A(1)-regs in flight
    loadA(0, vaA);
    stageB(0, 0);
    writeA(0, vaA);          // compiler-inserted wait covers loadA(0) only
    loadA(32, vaB);
    stageB(1, 32);
    stageB(2, 64);

    // body(T): wait{vmcnt(8): stageB(T) done; B(T+1),A(T+1),B(T+2) stay in
    // flight; lgkm(0): writeA(T) visible}; barrier; issue loadA(T+2) +
    // stageB(T+3); compute(T); writeA(T+1) from regs loaded at T-1.
#define BODY(T, VLD, VWR, CNT)                                                \
    {                                                                         \
        asm volatile("s_waitcnt vmcnt(" #CNT ") lgkmcnt(0)\n\ts_barrier" ::: "memory"); \
        if ((T) + 2 < 32) loadA(((T) + 2) * 32, VLD);                         \
        if ((T) + 3 < 32) stageB(((T) + 3) & 3, ((T) + 3) * 32);              \
        compute(T);                                                           \
        writeA(((T) + 1) & 1, VWR);                                           \
    }

#pragma unroll 1
    for (int tp = 0; tp < 15; ++tp) {
        int te = tp * 2;
        BODY(te, vaA, vaB, 8);       // even: load -> vaA, write from vaB
        BODY(te + 1, vaB, vaA, 8);   // odd:  load -> vaB, write from vaA
    }
    BODY(30, vaA, vaB, 6);           // T=30: no issues; retire stageB(30)
#undef BODY
    asm volatile("s_waitcnt vmcnt(0) lgkmcnt(0)\n\ts_barrier" ::: "memory");
    compute(31);

#pragma unroll
    for (int jn = 0; jn < 4; ++jn) {
        int col = n0 + wn * 64 + jn * 16 + l15;
        float bv = bias[col];
#pragma unroll
        for (int im = 0; im < 4; ++im) {
            int row0 = m0 + wm * 64 + im * 16 + q * 4;
#pragma unroll
            for (int r = 0; r < 4; ++r)
                Y[(size_t)(row0 + r) * 1024 + col] = acc[im][jn][r] * 0.03125f + bv;
        }
    }
}

// ---------------------------------------------------------------------------
extern "C" void kernel_launch(void* const* d_in, const int* in_sizes, int n_in,
                              void* d_out, int out_size, void* d_ws, size_t ws_size,
                              hipStream_t stream) {
    (void)in_sizes; (void)n_in; (void)out_size; (void)ws_size;
    const float* x    = (const float*)d_in[0];
    const float* kern = (const float*)d_in[1];
    const float* bias = (const float*)d_in[2];
    float* y = (float*)d_out;

    char* ws = (char*)d_ws;
    const size_t SZ = (size_t)1024 * 1024 * sizeof(_Float16);  // 2 MB
    _Float16* wh[2] = {(_Float16*)(ws + 0 * SZ), (_Float16*)(ws + 1 * SZ)};
    _Float16* wT[2] = {(_Float16*)(ws + 2 * SZ), (_Float16*)(ws + 3 * SZ)};
    _Float16* Sh    = (_Float16*)(ws + 4 * SZ);

    prep_w<<<dim3(16, 16), 256, 0, stream>>>(kern, wh[0], wT[0]);

    for (int it = 0; it < 20; ++it) {
        int c = it & 1, n = c ^ 1;
        // S_s = w_s^T w_s : A = BT = wT (both row-slabs of w^T, k contiguous)
        gemm1k<0><<<256, 512, 0, stream>>>(wT[c], wT[c], nullptr, Sh, nullptr);
        // w_next = 1.5 w - (0.5/1024) * (w_s * S_s); BT = S (symmetric)
        gemm1k<1><<<256, 512, 0, stream>>>(wh[c], Sh, wh[c], wh[n], wT[n]);
    }
    // final: y = (1/32) x * w_s + bias ; BT = wT (final parity lands in slot 0)
    gemm_big<<<2048, 256, 0, stream>>>(x, wT[0], bias, y);
}

// Round 5
// 676.255 us; speedup vs baseline: 2.2948x; 1.0725x over previous
//
#include <hip/hip_runtime.h>
#include <cstdint>

typedef _Float16 half8 __attribute__((ext_vector_type(8)));
typedef _Float16 half4v __attribute__((ext_vector_type(4)));
typedef float f32x4 __attribute__((ext_vector_type(4)));

__device__ __forceinline__ void async_copy16(const void* g, void* l) {
    __builtin_amdgcn_global_load_lds((const __attribute__((address_space(1))) void*)g,
                                     (__attribute__((address_space(3))) void*)l, 16, 0, 0);
}

// ---------------------------------------------------------------------------
// prep: w_s = kernel * (1/32)   [= 32 * (kernel/1024)], plus transposed copy.
// ---------------------------------------------------------------------------
__global__ __launch_bounds__(256) void prep_w(const float* __restrict__ K,
                                              _Float16* __restrict__ w0,
                                              _Float16* __restrict__ w0T) {
    __shared__ float tile[64][65];
    const int t  = threadIdx.x;
    const int bi = blockIdx.y * 64;
    const int bj = blockIdx.x * 64;
    const int r0 = t >> 4;
    const int c4 = (t & 15) * 4;
#pragma unroll
    for (int rr = 0; rr < 4; ++rr) {
        int r = r0 + rr * 16;
        f32x4 v = *(const f32x4*)&K[(size_t)(bi + r) * 1024 + bj + c4];
        v *= 0.03125f;
        half4v h;
        h[0] = (_Float16)v[0]; h[1] = (_Float16)v[1];
        h[2] = (_Float16)v[2]; h[3] = (_Float16)v[3];
        *(half4v*)&w0[(size_t)(bi + r) * 1024 + bj + c4] = h;
        tile[r][c4 + 0] = v[0]; tile[r][c4 + 1] = v[1];
        tile[r][c4 + 2] = v[2]; tile[r][c4 + 3] = v[3];
    }
    __syncthreads();
    const int cT = t >> 4;
    const int rT = (t & 15) * 4;
#pragma unroll
    for (int cc = 0; cc < 4; ++cc) {
        int c = cT + cc * 16;
        half4v h;
        h[0] = (_Float16)tile[rT + 0][c]; h[1] = (_Float16)tile[rT + 1][c];
        h[2] = (_Float16)tile[rT + 2][c]; h[3] = (_Float16)tile[rT + 3][c];
        *(half4v*)&w0T[(size_t)(bj + c) * 1024 + bi + rT] = h;
    }
}

// ---------------------------------------------------------------------------
// small 1024x1024x1024 GEMM:  C[m][n] = sum_k A[m][k] * BT[n][k]
// EPI==0: out = (fp16)acc                  (S_s = w_s^T w_s, via A=BT=wT)
// EPI==1: w' = 1.5*wcur - (0.5/1024)*acc   (+ transposed copy)
// v4 (round-4, retained): 4-buffer LDS (128 KB), 3-deep glds prefetch,
// counted vmcnt(8) steady, tail vmcnt(4)/vmcnt(0).
// NOTE: per-launch chain (round-1: persistent grid barrier costs ~30us/phase
// in agent-scope coherence). Do not re-fuse.
// ---------------------------------------------------------------------------
template <int EPI>
__global__ __launch_bounds__(512) void gemm1k(const _Float16* __restrict__ A,
                                              const _Float16* __restrict__ BT,
                                              const _Float16* __restrict__ wcur,
                                              _Float16* __restrict__ out,
                                              _Float16* __restrict__ outT) {
    __shared__ _Float16 sA[4][8192];   // 64 rows x 128 halves per buf (16 KB)
    __shared__ _Float16 sB[4][8192];   // total 128 KB
    const int t = threadIdx.x;
    const int b = blockIdx.x;
    const int xcd = b & 7, j = b >> 3;
    const int m0 = (((xcd & 1) << 3) + (j & 7)) << 6;   // 16 m-tiles
    const int n0 = (((xcd >> 1) << 2) + (j >> 3)) << 6; // 16 n-tiles
    const int ln = t & 63, wv = t >> 6;
    const int wm = wv >> 1, wn = wv & 1;     // 4 x 2 waves
    const int q  = ln >> 4, l15 = ln & 15;
    const int row0 = m0 + wm * 16 + q * 4;

    // EPI==1: prefetch wcur for the epilogue. Issued BEFORE the stages ->
    // oldest in the vmcnt FIFO; counted waits retire them first (harmless).
    float wpre[2][4];
    if (EPI == 1) {
#pragma unroll
        for (int jn = 0; jn < 2; ++jn) {
            int col = n0 + wn * 32 + jn * 16 + l15;
#pragma unroll
            for (int r = 0; r < 4; ++r)
                wpre[jn][r] = (float)wcur[(size_t)(row0 + r) * 1024 + col];
        }
    }

    f32x4 acc[2];
#pragma unroll
    for (int jn = 0; jn < 2; ++jn) {
        acc[jn][0] = 0.f; acc[jn][1] = 0.f;
        acc[jn][2] = 0.f; acc[jn][3] = 0.f;
    }

    auto stage = [&](int buf, int k0) {   // 4 vmcnt entries per thread
#pragma unroll
        for (int rnd = 0; rnd < 2; ++rnd) {
            int c = t + rnd * 512;          // granule 0..1023 (16 per row)
            int row = c >> 4, g = c & 15;
            int gs = g ^ (row & 15);        // XOR swizzle
            async_copy16(A + (size_t)(m0 + row) * 1024 + k0 + gs * 8, &sA[buf][c * 8]);
            async_copy16(BT + (size_t)(n0 + row) * 1024 + k0 + gs * 8, &sB[buf][c * 8]);
        }
    };
    auto frag = [&](const _Float16* s, int row, int kc) -> half8 {
        return *(const half8*)&s[row * 128 + ((kc ^ (row & 15)) << 3)];
    };
    auto dostep = [&](int buf) {
#pragma unroll
        for (int kk = 0; kk < 4; ++kk) {
            half8 a0 = frag(sA[buf], wm * 16 + l15, kk * 4 + q);
            half8 b0 = frag(sB[buf], wn * 32 + 0  + l15, kk * 4 + q);
            half8 b1 = frag(sB[buf], wn * 32 + 16 + l15, kk * 4 + q);
            acc[0] = __builtin_amdgcn_mfma_f32_16x16x32_f16(a0, b0, acc[0], 0, 0, 0);
            acc[1] = __builtin_amdgcn_mfma_f32_16x16x32_f16(a0, b1, acc[1], 0, 0, 0);
        }
    };

    stage(0, 0);
    stage(1, 128);
    stage(2, 256);
    // steady: at top of it, outstanding = stage(it)+stage(it+1)+stage(it+2)
    // = 12 entries; vmcnt(8) retires stage(it) only.
#pragma unroll 1
    for (int it = 0; it < 6; ++it) {
        asm volatile("s_waitcnt vmcnt(8)\n\ts_barrier" ::: "memory");
        if (it < 5) stage((it + 3) & 3, (it + 3) * 128);
        dostep(it & 3);
    }
    asm volatile("s_waitcnt vmcnt(4)\n\ts_barrier" ::: "memory");  // stage(6) done
    dostep(2);   // tile 6 -> buf 2
    asm volatile("s_waitcnt vmcnt(0)\n\ts_barrier" ::: "memory");  // stage(7) done
    dostep(3);   // tile 7 -> buf 3

    // epilogue
#pragma unroll
    for (int jn = 0; jn < 2; ++jn) {
        int col = n0 + wn * 32 + jn * 16 + l15;
        if (EPI == 0) {
#pragma unroll
            for (int r = 0; r < 4; ++r)
                out[(size_t)(row0 + r) * 1024 + col] = (_Float16)acc[jn][r];
        } else {
            half4v hT;
#pragma unroll
            for (int r = 0; r < 4; ++r) {
                float nv  = 1.5f * wpre[jn][r] - 4.8828125e-4f * acc[jn][r];
                _Float16 h = (_Float16)nv;
                out[(size_t)(row0 + r) * 1024 + col] = h;
                hT[r] = h;
            }
            *(half4v*)&outT[(size_t)col * 1024 + row0] = hT;
        }
    }
}

// ---------------------------------------------------------------------------
// big GEMM: Y[32768][1024] = (1/32) * X(f32, cvt->f16) * w_s  + bias
// v7: 256x256 tile, BK=64, 512 threads (8 waves = 2m x 4n; per wave 128x64 =
// 8x4 frags of 16x16x32). 16 K-steps. LDS 128 KB: sA[2]+sB[2] of 32 KB.
// Per wave per step: 24 ds_read_b128 for 64 MFMAs (0.375 reads/MFMA vs 0.5
// in the old 128x128 geometry) — rounds 2-4 showed the old shape is
// latency/LDS-structure-bound at 14% MfmaUtil regardless of pipeline depth.
// A: reg-staged f32 (coalesced f32x4 pairs) -> cvt -> SWIZZLED ds_write.
// B: glds with PRE-SWIZZLED global source (T21: linear dest + inv-swz src +
//    swz read; involution g ^= row&7 on 16B granules).
// Pipeline: B 1-deep (B is 2 MB, L2-resident per XCD), X 2-deep in regs
// (vaA/vaB, static parity); counted vmcnt(8) steady (retires B(t); X(t+1)
// 8 entries stay in flight), lgkm(0) for writeA visibility; writeA placed
// BEFORE compute to shorten va live range.
// Grid 512 blocks, 1 block/CU, 2 rounds; per-XCD: 8 m-slabs x 4 n-tiles,
// the 4 n-sharers of each X m-slab co-scheduled (X ~once from HBM).
// ---------------------------------------------------------------------------
__global__ __launch_bounds__(512) void gemm_big(const float* __restrict__ X,
                                                const _Float16* __restrict__ BT,
                                                const float* __restrict__ bias,
                                                float* __restrict__ Y) {
    __shared__ _Float16 sA[2][256 * 64];   // 32 KB per buf
    __shared__ _Float16 sB[2][256 * 64];   // 32 KB per buf
    const int t    = threadIdx.x;
    const int b    = blockIdx.x;           // 0..511
    const int xcd  = b & 7;
    const int j    = b >> 3;               // 0..63
    const int rnd_ = j >> 5;               // dispatch round 0..1
    const int jj   = j & 31;
    const int mt   = rnd_ * 64 + xcd * 8 + (jj >> 2);  // 0..127
    const int nt   = jj & 3;                           // 0..3
    const int m0 = mt * 256, n0 = nt * 256;
    const int ln = t & 63, wv = t >> 6;    // 8 waves
    const int wm = wv >> 2, wn = wv & 3;   // 2m x 4n
    const int q  = ln >> 4, l15 = ln & 15;

    f32x4 acc[8][4];
#pragma unroll
    for (int i = 0; i < 8; ++i)
#pragma unroll
        for (int jn = 0; jn < 4; ++jn) {
            acc[i][jn][0] = 0.f; acc[i][jn][1] = 0.f;
            acc[i][jn][2] = 0.f; acc[i][jn][3] = 0.f;
        }

    // thread t covers 16B-granules c = t + rnd*512 (rnd 0..3); row = c>>3,
    // g = c&7 (8 granules of 8 halves per row of 64 halves).
    auto loadX = [&](int k0, f32x4* va) {   // 8 vmcnt entries, fully coalesced
#pragma unroll
        for (int rnd = 0; rnd < 4; ++rnd) {
            int c = t + rnd * 512;
            int row = c >> 3, g = c & 7;
            const float* p = &X[(size_t)(m0 + row) * 1024 + k0 + g * 8];
            va[rnd * 2 + 0] = *(const f32x4*)p;
            va[rnd * 2 + 1] = *(const f32x4*)(p + 4);
        }
    };
    auto writeA = [&](int buf, const f32x4* va) {  // swizzled ds_write_b128 x4
#pragma unroll
        for (int rnd = 0; rnd < 4; ++rnd) {
            int c = t + rnd * 512;
            int row = c >> 3, g = c & 7;
            half8 h;
#pragma unroll
            for (int i = 0; i < 4; ++i) {
                h[i]     = (_Float16)va[rnd * 2 + 0][i];
                h[4 + i] = (_Float16)va[rnd * 2 + 1][i];
            }
            *(half8*)&sA[buf][row * 64 + ((g ^ (row & 7)) << 3)] = h;
        }
    };
    auto stageB = [&](int buf, int k0) {    // 4 vmcnt entries; linear dest
#pragma unroll
        for (int rnd = 0; rnd < 4; ++rnd) {
            int c = t + rnd * 512;
            int row = c >> 3, g = c & 7;
            int gs = g ^ (row & 7);         // inverse-swizzled source
            async_copy16(BT + (size_t)(n0 + row) * 1024 + k0 + gs * 8,
                         &sB[buf][c * 8]);
        }
    };
    auto compute = [&](int tb) {
        const _Float16* A_ = sA[tb & 1];
        const _Float16* B_ = sB[tb & 1];
#pragma unroll
        for (int kk = 0; kk < 2; ++kk) {
            const int gidx = kk * 4 + q;
            half8 a[8], bf[4];
#pragma unroll
            for (int im = 0; im < 8; ++im) {
                int row = wm * 128 + im * 16 + l15;
                a[im] = *(const half8*)&A_[row * 64 + ((gidx ^ (row & 7)) << 3)];
            }
#pragma unroll
            for (int jn = 0; jn < 4; ++jn) {
                int row = wn * 64 + jn * 16 + l15;
                bf[jn] = *(const half8*)&B_[row * 64 + ((gidx ^ (row & 7)) << 3)];
            }
#pragma unroll
            for (int im = 0; im < 8; ++im)
#pragma unroll
                for (int jn = 0; jn < 4; ++jn)
                    acc[im][jn] = __builtin_amdgcn_mfma_f32_16x16x32_f16(
                        a[im], bf[jn], acc[im][jn], 0, 0, 0);
        }
    };

    f32x4 vaA[8], vaB[8];
    // prologue: A(0)->LDS (compiler waits its 8 loads; B(0)'s 4 glds stay
    // outstanding); X(1)->regs.
    loadX(0, vaA);
    stageB(0, 0);
    writeA(0, vaA);
    loadX(64, vaB);

    // step T: top wait {vmcnt(8): retires B(T) (X(T+1)'s 8 entries remain);
    // lgkm(0): writeA(T) visible}; barrier; issue B(T+1) (buf last read at
    // T-1, all waves past barrier), X(T+2) into freed set; writeA(T+1)
    // (other sA buf; compiler waits X(T+1) with its own counted vmcnt);
    // compute(T).
#define BODY(T, VLD, VWR, CNT)                                                \
    {                                                                         \
        asm volatile("s_waitcnt vmcnt(" #CNT ") lgkmcnt(0)\n\ts_barrier" ::: "memory"); \
        if ((T) + 1 < 16) stageB(((T) + 1) & 1, ((T) + 1) * 64);              \
        if ((T) + 2 < 16) loadX(((T) + 2) * 64, VLD);                         \
        if ((T) + 1 < 16) writeA(((T) + 1) & 1, VWR);                         \
        compute(T);                                                           \
    }

#pragma unroll 1
    for (int tp = 0; tp < 7; ++tp) {
        int te = tp * 2;
        BODY(te, vaA, vaB, 8);       // even: X->vaA, writeA from vaB
        BODY(te + 1, vaB, vaA, 8);   // odd:  X->vaB, writeA from vaA
    }
    BODY(14, vaA, vaB, 8);           // stageB(15)+writeA(15,vaB); no loadX
    BODY(15, vaB, vaA, 0);           // guards prune all issues; drain + compute
#undef BODY

    // epilogue: Y = acc * (1/32) + bias
#pragma unroll
    for (int jn = 0; jn < 4; ++jn) {
        int col = n0 + wn * 64 + jn * 16 + l15;
        float bv = bias[col];
#pragma unroll
        for (int im = 0; im < 8; ++im) {
            int row0 = m0 + wm * 128 + im * 16 + q * 4;
#pragma unroll
            for (int r = 0; r < 4; ++r)
                Y[(size_t)(row0 + r) * 1024 + col] = acc[im][jn][r] * 0.03125f + bv;
        }
    }
}

// ---------------------------------------------------------------------------
extern "C" void kernel_launch(void* const* d_in, const int* in_sizes, int n_in,
                              void* d_out, int out_size, void* d_ws, size_t ws_size,
                              hipStream_t stream) {
    (void)in_sizes; (void)n_in; (void)out_size; (void)ws_size;
    const float* x    = (const float*)d_in[0];
    const float* kern = (const float*)d_in[1];
    const float* bias = (const float*)d_in[2];
    float* y = (float*)d_out;

    char* ws = (char*)d_ws;
    const size_t SZ = (size_t)1024 * 1024 * sizeof(_Float16);  // 2 MB
    _Float16* wh[2] = {(_Float16*)(ws + 0 * SZ), (_Float16*)(ws + 1 * SZ)};
    _Float16* wT[2] = {(_Float16*)(ws + 2 * SZ), (_Float16*)(ws + 3 * SZ)};
    _Float16* Sh    = (_Float16*)(ws + 4 * SZ);

    prep_w<<<dim3(16, 16), 256, 0, stream>>>(kern, wh[0], wT[0]);

    for (int it = 0; it < 20; ++it) {
        int c = it & 1, n = c ^ 1;
        // S_s = w_s^T w_s : A = BT = wT (both row-slabs of w^T, k contiguous)
        gemm1k<0><<<256, 512, 0, stream>>>(wT[c], wT[c], nullptr, Sh, nullptr);
        // w_next = 1.5 w - (0.5/1024) * (w_s * S_s); BT = S (symmetric)
        gemm1k<1><<<256, 512, 0, stream>>>(wh[c], Sh, wh[c], wh[n], wT[n]);
    }
    // final: y = (1/32) x * w_s + bias ; BT = wT (final parity lands in slot 0)
    gemm_big<<<512, 512, 0, stream>>>(x, wT[0], bias, y);
}